// Round 8
// baseline (104.185 us; speedup 1.0000x reference)
//
#include <hip/hip_runtime.h>

// SimpleRNN: B=8192, T=1024, H=8.  h_{t+1} = tanh(pre_t + h_t @ W_hh^T); out = sigmoid(h@W_fc^T+b_fc)
// Quad-per-batch layout; lane p (0..3) owns h[p], h[p+4]. DPP quad_perm xor-systolic matvec.
// v3: tanh tail = Pade(5,4) rational (1 transcendental hop: rcp) instead of exp2+rcp (2 hops).
//     Theory: dependent-use latency of trans ops (~60-80cy each) dominates the 205cy/step chain.

#define T_LEN 1024
#define DPP_XOR1 0xB1  // quad_perm(1,0,3,2)
#define DPP_XOR2 0x4E  // quad_perm(2,3,0,1)
#define DPP_XOR3 0x1B  // quad_perm(3,2,1,0)

template <int CTRL>
__device__ __forceinline__ float fdpp(float v) {
    int i = __builtin_bit_cast(int, v);
    int r = __builtin_amdgcn_mov_dpp(i, CTRL, 0xF, 0xF, true);
    return __builtin_bit_cast(float, r);
}

// tanh(z) ~= z*(945 + 105 t + t^2) / (945 + 420 t + 15 t^2),  t = z^2   (CF truncation, err<~5e-4)
// Overshoots |1| slightly for |z|>3.9 -> clamp. Only ONE transcendental hop (rcp) on the chain.
__device__ __forceinline__ float tanh_pade(float z) {
    float t = z * z;
    float n = __builtin_fmaf(t, t + 105.0f, 945.0f);
    float d = __builtin_fmaf(t, __builtin_fmaf(t, 15.0f, 420.0f), 945.0f);
    float y = (z * n) * __builtin_amdgcn_rcpf(d);
    return fminf(1.0f, fmaxf(-1.0f, y));
}

__device__ __forceinline__ float fast_sigmoid(float z) {
    float e = __builtin_amdgcn_exp2f(z * -1.4426950408889634f);
    return __builtin_amdgcn_rcpf(1.0f + e);
}

struct Wq { float wA[4], wB[4], wC[4], wD[4]; };

// pre0/pre1 = x_t*wih + bias, h-independent (off the chain).
__device__ __forceinline__ void step(float pre0, float pre1, float& h0, float& h1, const Wq& w) {
    float u0 = __builtin_fmaf(h0, w.wA[0], pre0);
    float v0 = h1 * w.wB[0];
    float u1 = __builtin_fmaf(h0, w.wC[0], pre1);
    float v1 = h1 * w.wD[0];

    float a = fdpp<DPP_XOR1>(h0), c = fdpp<DPP_XOR1>(h1);
    u0 = __builtin_fmaf(a, w.wA[1], u0); v0 = __builtin_fmaf(c, w.wB[1], v0);
    u1 = __builtin_fmaf(a, w.wC[1], u1); v1 = __builtin_fmaf(c, w.wD[1], v1);

    a = fdpp<DPP_XOR2>(h0); c = fdpp<DPP_XOR2>(h1);
    u0 = __builtin_fmaf(a, w.wA[2], u0); v0 = __builtin_fmaf(c, w.wB[2], v0);
    u1 = __builtin_fmaf(a, w.wC[2], u1); v1 = __builtin_fmaf(c, w.wD[2], v1);

    a = fdpp<DPP_XOR3>(h0); c = fdpp<DPP_XOR3>(h1);
    u0 = __builtin_fmaf(a, w.wA[3], u0); v0 = __builtin_fmaf(c, w.wB[3], v0);
    u1 = __builtin_fmaf(a, w.wC[3], u1); v1 = __builtin_fmaf(c, w.wD[3], v1);

    h0 = tanh_pade(u0 + v0);
    h1 = tanh_pade(u1 + v1);
}

__global__ __launch_bounds__(64) void rnn_quad_kernel(
    const float* __restrict__ x, const float* __restrict__ W_ih,
    const float* __restrict__ W_hh, const float* __restrict__ b_ih,
    const float* __restrict__ b_hh, const float* __restrict__ W_fc,
    const float* __restrict__ b_fc, float* __restrict__ out, int B)
{
    const int tid = blockIdx.x * 64 + threadIdx.x;
    const int p = tid & 3;
    const int b = tid >> 2;
    if (b >= B) return;

    Wq w;
#pragma unroll
    for (int r = 0; r < 4; ++r) {
        const int k = p ^ r;
        w.wA[r] = W_hh[p * 8 + k];
        w.wB[r] = W_hh[p * 8 + k + 4];
        w.wC[r] = W_hh[(p + 4) * 8 + k];
        w.wD[r] = W_hh[(p + 4) * 8 + k + 4];
    }
    const float wih0  = W_ih[p];
    const float wih1  = W_ih[p + 4];
    const float bias0 = b_ih[p] + b_hh[p];
    const float bias1 = b_ih[p + 4] + b_hh[p + 4];
    const float wfc0 = W_fc[p], wfc1 = W_fc[p + 4];
    const float bfc = b_fc[0];

    const float* xb = x + (size_t)b * T_LEN;
    float h0 = 0.0f, h1 = 0.0f;

    float4 cur0 = *(const float4*)(xb + 0);
    float4 cur1 = *(const float4*)(xb + 4);
    float4 nxt0 = *(const float4*)(xb + 8);
    float4 nxt1 = *(const float4*)(xb + 12);

#pragma unroll 1
    for (int t0 = 0; t0 < T_LEN; t0 += 8) {
        float4 pf0, pf1;
        const bool more = (t0 + 16) < T_LEN;
        if (more) {
            pf0 = *(const float4*)(xb + t0 + 16);
            pf1 = *(const float4*)(xb + t0 + 20);
        }
        // input projection hoisted off the recurrence chain
        float pa[8], pb[8];
        pa[0] = __builtin_fmaf(cur0.x, wih0, bias0); pb[0] = __builtin_fmaf(cur0.x, wih1, bias1);
        pa[1] = __builtin_fmaf(cur0.y, wih0, bias0); pb[1] = __builtin_fmaf(cur0.y, wih1, bias1);
        pa[2] = __builtin_fmaf(cur0.z, wih0, bias0); pb[2] = __builtin_fmaf(cur0.z, wih1, bias1);
        pa[3] = __builtin_fmaf(cur0.w, wih0, bias0); pb[3] = __builtin_fmaf(cur0.w, wih1, bias1);
        pa[4] = __builtin_fmaf(cur1.x, wih0, bias0); pb[4] = __builtin_fmaf(cur1.x, wih1, bias1);
        pa[5] = __builtin_fmaf(cur1.y, wih0, bias0); pb[5] = __builtin_fmaf(cur1.y, wih1, bias1);
        pa[6] = __builtin_fmaf(cur1.z, wih0, bias0); pb[6] = __builtin_fmaf(cur1.z, wih1, bias1);
        pa[7] = __builtin_fmaf(cur1.w, wih0, bias0); pb[7] = __builtin_fmaf(cur1.w, wih1, bias1);

#pragma unroll
        for (int i = 0; i < 8; ++i)
            step(pa[i], pb[i], h0, h1, w);

        cur0 = nxt0; cur1 = nxt1;
        if (more) { nxt0 = pf0; nxt1 = pf1; }
    }

    float s = __builtin_fmaf(h0, wfc0, h1 * wfc1);
    s += fdpp<DPP_XOR1>(s);
    s += fdpp<DPP_XOR2>(s);
    if (p == 0) out[b] = fast_sigmoid(s + bfc);
}

extern "C" void kernel_launch(void* const* d_in, const int* in_sizes, int n_in,
                              void* d_out, int out_size, void* d_ws, size_t ws_size,
                              hipStream_t stream) {
    const float* x    = (const float*)d_in[0];
    const float* W_ih = (const float*)d_in[1];
    const float* W_hh = (const float*)d_in[2];
    const float* b_ih = (const float*)d_in[3];
    const float* b_hh = (const float*)d_in[4];
    const float* W_fc = (const float*)d_in[5];
    const float* b_fc = (const float*)d_in[6];
    float* out = (float*)d_out;

    const int B = in_sizes[0] / T_LEN;            // 8192
    const int threads = B * 4;
    const int grid = (threads + 63) / 64;
    rnn_quad_kernel<<<grid, 64, 0, stream>>>(x, W_ih, W_hh, b_ih, b_hh, W_fc, b_fc, out, B);
}